// Round 8
// baseline (260.060 us; speedup 1.0000x reference)
//
#include <hip/hip_runtime.h>
#include <stdint.h>

// MPLayer edge: 16-row waves, 16x16x32 MFMA, swapped operands (A=W,B=act) for
// L1/L2, non-swapped L3. All weights in LDS as fragment-contiguous blobs with
// k-permutation sigma(g,e)=16(g>>1)+4(g&1)+(e&3)+8(e>>2) (what 2
// permlane32_swaps produce from packed C/D tiles). acc3 streamed per 32-col
// chunk => ~110 regs => 4 waves/SIMD at 1024-thr blocks (16 waves, 256 rows).
// R8 fix vs R7: sAgg zeroing covered only [0,512) (else-chain range bug with
// 1024 threads) -> stale LDS accumulated into groups 2..4. Now zeroed fully.
// ws: agg fp32 [9600][192] (7,372,800 B) then bf16 weights (356,480 B).

#define ALPHA 0.2f
#define EDGE_ROWS 720000
#define EDGE_BLOCKS 2813  // ceil(720000/256), 256 rows/block

typedef __attribute__((ext_vector_type(8))) short short8v;
typedef __attribute__((ext_vector_type(16))) float float16v;
typedef __attribute__((ext_vector_type(4))) float float4v;

__device__ __forceinline__ uint16_t f2bf(float f) {
  uint32_t u = __builtin_bit_cast(uint32_t, f);
  u += 0x7FFFu + ((u >> 16) & 1u);   // round-to-nearest-even
  return (uint16_t)(u >> 16);
}
__device__ __forceinline__ float bf2f(uint16_t h) {
  uint32_t u = ((uint32_t)h) << 16;
  return __builtin_bit_cast(float, u);
}
__device__ __forceinline__ float lrelu(float v) { return fmaxf(v, ALPHA * v); }
__device__ __forceinline__ float16v zero16() {
  float16v z;
#pragma unroll
  for (int i = 0; i < 16; ++i) z[i] = 0.f;
  return z;
}
__device__ __forceinline__ float4v zero4() {
  float4v z;
#pragma unroll
  for (int i = 0; i < 4; ++i) z[i] = 0.f;
  return z;
}
// 16B LDS fragment read (ds_read_b128)
__device__ __forceinline__ short8v lfrag(const uint16_t* p) {
  union { uint4 u; short8v v; } t;
  t.u = *(const uint4*)p;
  return t.v;
}
// 8 consecutive bf16 from global as two 8B loads
__device__ __forceinline__ short8v load8(const uint16_t* p) {
  union { uint2 u2[2]; short8v v; } t;
  t.u2[0] = *(const uint2*)(p);
  t.u2[1] = *(const uint2*)(p + 4);
  return t.v;
}
__device__ __forceinline__ short8v frag32(const uint16_t* base, int stride, int r0,
                                          int k0, int lane) {
  int row = r0 + (lane & 31);
  return load8(base + row * stride + k0 + ((lane >> 5) << 3));
}
__device__ __forceinline__ uint32_t pk2(float a, float b) {
  uint32_t r;
  asm("v_cvt_pk_bf16_f32 %0, %1, %2" : "=v"(r) : "v"(a), "v"(b));
  return r;
}
// swap: a[32..63] <-> b[0..31]
__device__ __forceinline__ void plswap(uint32_t& a, uint32_t& b) {
  asm volatile("v_permlane32_swap_b32 %0, %1" : "+v"(a), "+v"(b));
}
__device__ __forceinline__ short8v mk8(uint32_t w0, uint32_t w1, uint32_t w2,
                                       uint32_t w3) {
  union { uint32_t u[4]; short8v v; } t;
  t.u[0] = w0; t.u[1] = w1; t.u[2] = w2; t.u[3] = w3;
  return t.v;
}

// ---------------- prep: weights -> bf16 fragment blobs + node layouts ----------
// sigma(g,e): k-slot of lane-group g, elem e (both A and B fragments).
// Edge frag blob: frag[f][l][e] = W[kchunk*32 + sigma(l>>4,e)][ntile*16 + (l&15)]
#define EW1 3072                 // 6 frags  (L1: K-chunk 0, tiles 0..5; k<7 W, k==7 bias)
#define EW2 15360                // 30 frags (L2: chunk*10+tile, K=96)
#define EW3 30720                // 60 frags (L3: chunk*12+tile, K=160)
#define EDGE_FRAGS (EW1+EW2+EW3) // 49152
#define S3 (256*228)             // fnw1T[256][228] k<195
#define S4 (256*260)             // fnw2T[256][260] k<256
#define S5 (16*260)              // fnw3T[16][260]  n<3,k<256
#define PREP_TOTAL (EDGE_FRAGS+S3+S4+S5)  // 178240

__global__ void prep_kernel(const float* __restrict__ few1, const float* __restrict__ feb1,
                            const float* __restrict__ few2, const float* __restrict__ few3,
                            const float* __restrict__ fnw1, const float* __restrict__ fnw2,
                            const float* __restrict__ fnw3,
                            uint16_t* __restrict__ wsb) {
  int idx = blockIdx.x * 256 + threadIdx.x;
  if (idx >= PREP_TOTAL) return;
  float v = 0.f;
  int j = idx;
  if (j < EDGE_FRAGS) {
    int f = j >> 9;               // frag id
    int l = (j >> 3) & 63, e = j & 7;
    int g = l >> 4, s = l & 15;
    int sig = 16 * (g >> 1) + 4 * (g & 1) + (e & 3) + ((e >= 4) ? 8 : 0);
    if (f < 6) {                  // W1: tiles 0..5, chunk 0
      int k = sig, n = f * 16 + s;
      if (k < 7) v = few1[k * 96 + n];
      else if (k == 7) v = feb1[n];
    } else if (f < 36) {          // W2
      int ff = f - 6, chunk = ff / 10, tile = ff % 10;
      int k = chunk * 32 + sig, n = tile * 16 + s;
      v = few2[k * 160 + n];      // k<96, n<160 always
    } else {                      // W3
      int ff = f - 36, chunk = ff / 12, tile = ff % 12;
      int k = chunk * 32 + sig, n = tile * 16 + s;
      v = few3[k * 192 + n];      // k<160, n<192 always
    }
  } else if ((j -= EDGE_FRAGS) < S3) {
    int n = j / 228, k = j % 228;
    if (k < 195) v = fnw1[k * 256 + n];
  } else if ((j -= S3) < S4) {
    int n = j / 260, k = j % 260;
    if (k < 256) v = fnw2[k * 256 + n];
  } else {
    j -= S4;
    int n = j / 260, k = j % 260;
    if (n < 3 && k < 256) v = fnw3[k * 3 + n];
  }
  wsb[idx] = f2bf(v);
}

// ---------------- edge MLP + aggregation ----------------
// 2813 blocks x 1024 thr (16 waves x 16 rows). Weights staged once to LDS.
#define MFMA16(A, B, C) __builtin_amdgcn_mfma_f32_16x16x32_bf16(A, B, C, 0, 0, 0)

__global__ __launch_bounds__(1024, 4)
void edge_kernel(const float* __restrict__ x,
                 const float* __restrict__ feb2, const float* __restrict__ feb3,
                 const uint16_t* __restrict__ wf, float* __restrict__ agg) {
  __shared__ __align__(16) uint16_t sWf[EDGE_FRAGS];  // 98304 B
  __shared__ __align__(16) float sB2[160];
  __shared__ __align__(16) float sB3[192];
  __shared__ float sAgg[5 * 192];                     // => 103552 B total

  const int t = threadIdx.x, w = t >> 6, l = t & 63, g = l >> 4, li = l & 15;
  const int R0 = blockIdx.x * 256;
  const int rowbase = R0 + w * 16;

  {  // stage weights + biases, zero sAgg (independent ranges, NOT else-chained)
    const uint4* src = (const uint4*)wf;
    uint4* dst = (uint4*)sWf;
#pragma unroll
    for (int u = 0; u < 6; ++u) dst[t + u * 1024] = src[t + u * 1024];
    if (t < 160) sB2[t] = feb2[t];
    if (t >= 192 && t < 384) sB3[t - 192] = feb3[t - 192];
    if (t >= 64) sAgg[t - 64] = 0.f;   // t-64 in [0,960): all 960 entries
  }
  __syncthreads();

  // per-lane weight-fragment base: frag[f][l][e] -> sWf + f*512 + l*8
  const uint16_t* wl = sWf + (l << 3);

  // ---- features for this lane's row (row = rowbase + li; all 4 g-groups same) --
  int rr = rowbase + li;
  if (rr >= EDGE_ROWS) rr = EDGE_ROWS - 1;
  int b = rr / 5625, rb = rr % 5625;
  int ii = rb / 75, jj = rb % 75;
  const float* xb = x + b * 225;
  float xi0 = xb[ii * 3], xi1 = xb[ii * 3 + 1], xi2 = xb[ii * 3 + 2];
  float xj0 = xb[jj * 3], xj1 = xb[jj * 3 + 1], xj2 = xb[jj * 3 + 2];
  float d0 = xj0 - xi0 + 1e-12f, d1 = xj1 - xi1 + 1e-12f, d2 = xj2 - xi2 + 1e-12f;
  float dist = sqrtf(d0 * d0 + d1 * d1 + d2 * d2);
  // A0 B-frag via sigma: g0 e0..3 -> k0..3 = {xi0,xi1,xi2,xj0},
  // g1 e0..3 -> k4..7 = {xj1,xj2,dist,1.0(bias)}; g2/g3 + e>=4 zero (W1 zero too).
  short8v a0 = {0, 0, 0, 0, 0, 0, 0, 0};
  if (g == 0) {
    a0[0] = (short)f2bf(xi0); a0[1] = (short)f2bf(xi1);
    a0[2] = (short)f2bf(xi2); a0[3] = (short)f2bf(xj0);
  } else if (g == 1) {
    a0[0] = (short)f2bf(xj1); a0[1] = (short)f2bf(xj2);
    a0[2] = (short)f2bf(dist); a0[3] = (short)0x3F80;
  }

  // ---- L1: 6 tiles, K=32 (one chunk), bias folded at k=7 ----
  float4v c1[6];
#pragma unroll
  for (int n = 0; n < 6; ++n)
    c1[n] = MFMA16(lfrag(wl + n * 512), a0, zero4());
  short8v h1f[3];
#pragma unroll
  for (int c = 0; c < 3; ++c) {
    float4v A = c1[2 * c], B = c1[2 * c + 1];
    uint32_t a0w = pk2(lrelu(A[0]), lrelu(A[1]));
    uint32_t a1w = pk2(lrelu(A[2]), lrelu(A[3]));
    uint32_t b0w = pk2(lrelu(B[0]), lrelu(B[1]));
    uint32_t b1w = pk2(lrelu(B[2]), lrelu(B[3]));
    plswap(a0w, b0w);
    plswap(a1w, b1w);
    h1f[c] = mk8(a0w, a1w, b0w, b1w);
  }

  // ---- L2 (streamed per 32-col pair) fused with L3 ----
  float4v c3[12];
#pragma unroll
  for (int n = 0; n < 12; ++n) c3[n] = zero4();
  const uint16_t* W2f = wl + EW1;
  const uint16_t* W3f = wl + EW1 + EW2;
#pragma unroll
  for (int p = 0; p < 5; ++p) {
    float4v cA = zero4(), cB = zero4();
#pragma unroll
    for (int c = 0; c < 3; ++c) {
      cA = MFMA16(lfrag(W2f + (c * 10 + 2 * p) * 512), h1f[c], cA);
      cB = MFMA16(lfrag(W2f + (c * 10 + 2 * p + 1) * 512), h1f[c], cB);
    }
    float4 bA = *(const float4*)(&sB2[(2 * p) * 16 + g * 4]);
    float4 bB = *(const float4*)(&sB2[(2 * p + 1) * 16 + g * 4]);
    uint32_t wA0 = pk2(lrelu(cA[0] + bA.x), lrelu(cA[1] + bA.y));
    uint32_t wA1 = pk2(lrelu(cA[2] + bA.z), lrelu(cA[3] + bA.w));
    uint32_t wB0 = pk2(lrelu(cB[0] + bB.x), lrelu(cB[1] + bB.y));
    uint32_t wB1 = pk2(lrelu(cB[2] + bB.z), lrelu(cB[3] + bB.w));
    plswap(wA0, wB0);
    plswap(wA1, wB1);
    short8v h2f = mk8(wA0, wA1, wB0, wB1);
    // L3 chunk p: A = acts (row=li), B = W3 (col = out n)
#pragma unroll
    for (int n = 0; n < 12; ++n)
      c3[n] = MFMA16(h2f, lfrag(W3f + (p * 12 + n) * 512), c3[n]);
  }

  // ---- finalize: bias + lrelu + masked j-sum (rows = g*4+r), <=2 groups ----
  {
    const int gbase = R0 / 75;
    const int gl0 = rowbase / 75 - gbase;      // 0..4
    const int sb = 75 - rowbase % 75;          // rows < sb -> group gl0
    const int vlim = EDGE_ROWS - rowbase;      // rows >= vlim invalid
#pragma unroll
    for (int n = 0; n < 12; ++n) {
      float bias = sB3[n * 16 + li];
      float p0 = 0.f, p1 = 0.f;
#pragma unroll
      for (int r = 0; r < 4; ++r) {
        int jr = g * 4 + r;
        float v = lrelu(c3[n][r] + bias);
        v = (jr < vlim) ? v : 0.f;
        if (jr < sb) p0 += v; else p1 += v;
      }
      p0 += __shfl_xor(p0, 16); p0 += __shfl_xor(p0, 32);
      p1 += __shfl_xor(p1, 16); p1 += __shfl_xor(p1, 32);
      if (l < 16 && vlim > 0) {
        atomicAdd(&sAgg[gl0 * 192 + n * 16 + li], p0);
        if (sb < 16) atomicAdd(&sAgg[(gl0 + 1) * 192 + n * 16 + li], p1);
      }
    }
  }

  __syncthreads();
  if (t < 960) {  // flush block-local group sums (boundary groups shared)
    int gg = R0 / 75 + t / 192;
    float v = sAgg[t];
    if (gg < 9600 && v != 0.f) atomicAdd(&agg[gg * 192 + (t % 192)], v);
  }
}

// ---------------- node MLP (unchanged, working) ----------------
__global__ __launch_bounds__(512, 1)
void node_kernel(const float* __restrict__ x, const float* __restrict__ agg,
                 const float* __restrict__ fnb1, const float* __restrict__ fnb2,
                 const float* __restrict__ fnb3,
                 const uint16_t* __restrict__ fw1T, const uint16_t* __restrict__ fw2T,
                 const uint16_t* __restrict__ fw3T, float* __restrict__ out) {
  __shared__ __align__(16) uint16_t sY[64 * 228];
  __shared__ __align__(16) uint16_t sH1[64 * 260];
  __shared__ __align__(16) uint16_t sH2[64 * 260];
  __shared__ __align__(16) uint16_t sW[128 * 228];

  const int t = threadIdx.x;
  const int w = t >> 6, l = t & 63;
  const int n0 = blockIdx.x * 64;

  for (int u = t; u < 64 * 228; u += 512) {  // y hi/lo split
    int m = u / 228, c = u % 228;
    float v;
    if (c < 192) v = agg[(n0 + m) * 192 + c];
    else if (c < 195) v = x[(n0 + m) * 3 + (c - 192)];
    else v = 0.f;
    uint16_t hh = f2bf(v);
    sY[u] = hh;
    sH2[m * 260 + c] = f2bf(v - bf2f(hh));
  }
  __syncthreads();

  for (int p = 0; p < 2; ++p) {  // L1: hi+lo double MFMA
    const uint4* s = (const uint4*)(fw1T + p * 128 * 228);
    uint4* d = (uint4*)sW;
    for (int u = t; u < (128 * 228 * 2) / 16; u += 512) d[u] = s[u];
    __syncthreads();
    {
      int mt = w & 1, ntl = w >> 1;
      float16v acc = zero16();
      for (int kt = 0; kt < 14; ++kt) {
        short8v bb = frag32(sW, 228, ntl * 32, kt * 16, l);
        short8v ah = frag32(sY, 228, mt * 32, kt * 16, l);
        acc = __builtin_amdgcn_mfma_f32_32x32x16_bf16(ah, bb, acc, 0, 0, 0);
        short8v al = frag32(sH2, 260, mt * 32, kt * 16, l);
        acc = __builtin_amdgcn_mfma_f32_32x32x16_bf16(al, bb, acc, 0, 0, 0);
      }
      int col = (p * 4 + ntl) * 32 + (l & 31);
      float bias = fnb1[col];
#pragma unroll
      for (int r = 0; r < 16; ++r) {
        int row = (r & 3) + ((r >> 2) << 3) + ((l >> 5) << 2);
        sH1[(mt * 32 + row) * 260 + col] = f2bf(lrelu(acc[r] + bias));
      }
    }
    __syncthreads();
  }
  for (int q = 0; q < 4; ++q) {  // L2
    const uint4* s = (const uint4*)(fw2T + q * 64 * 260);
    uint4* d = (uint4*)sW;
    for (int u = t; u < (64 * 260 * 2) / 16; u += 512) d[u] = s[u];
    __syncthreads();
    if (w < 4) {
      int mt = w & 1, ntl = w >> 1;
      float16v acc = zero16();
      for (int kt = 0; kt < 16; ++kt) {
        short8v a = frag32(sH1, 260, mt * 32, kt * 16, l);
        short8v bb = frag32(sW, 260, ntl * 32, kt * 16, l);
        acc = __builtin_amdgcn_mfma_f32_32x32x16_bf16(a, bb, acc, 0, 0, 0);
      }
      int col = (q * 2 + ntl) * 32 + (l & 31);
      float bias = fnb2[col];
#pragma unroll
      for (int r = 0; r < 16; ++r) {
        int row = (r & 3) + ((r >> 2) << 3) + ((l >> 5) << 2);
        sH2[(mt * 32 + row) * 260 + col] = f2bf(lrelu(acc[r] + bias));
      }
    }
    __syncthreads();
  }
  if (w < 4) {  // L3: 256->3 linear, 16x16x32
    int mt = w;
    float4v acc = zero4();
    for (int kt = 0; kt < 8; ++kt) {
      short8v a = load8(sH2 + (mt * 16 + (l & 15)) * 260 + kt * 32 + ((l >> 4) << 3));
      short8v bb = load8(fw3T + (l & 15) * 260 + kt * 32 + ((l >> 4) << 3));
      acc = __builtin_amdgcn_mfma_f32_16x16x32_bf16(a, bb, acc, 0, 0, 0);
    }
    int col = l & 15;
    if (col < 3) {
      float bias = fnb3[col];
#pragma unroll
      for (int r = 0; r < 4; ++r) {
        int row = ((l >> 4) << 2) + r;
        out[(n0 + mt * 16 + row) * 3 + col] = acc[r] + bias;
      }
    }
  }
}

extern "C" void kernel_launch(void* const* d_in, const int* in_sizes, int n_in,
                              void* d_out, int out_size, void* d_ws, size_t ws_size,
                              hipStream_t stream) {
  (void)in_sizes; (void)n_in; (void)out_size; (void)ws_size;
  const float* x    = (const float*)d_in[0];
  const float* few1 = (const float*)d_in[1];
  const float* feb1 = (const float*)d_in[2];
  const float* few2 = (const float*)d_in[3];
  const float* feb2 = (const float*)d_in[4];
  const float* few3 = (const float*)d_in[5];
  const float* feb3 = (const float*)d_in[6];
  const float* fnw1 = (const float*)d_in[7];
  const float* fnb1 = (const float*)d_in[8];
  const float* fnw2 = (const float*)d_in[9];
  const float* fnb2 = (const float*)d_in[10];
  const float* fnw3 = (const float*)d_in[11];
  const float* fnb3 = (const float*)d_in[12];
  float* out = (float*)d_out;

  float* agg = (float*)d_ws;
  uint16_t* wsb = (uint16_t*)((char*)d_ws + 9600 * 192 * 4);
  const uint16_t* wfe  = wsb;                    // edge fragment blob
  const uint16_t* fw1T = wsb + EDGE_FRAGS;
  const uint16_t* fw2T = wsb + EDGE_FRAGS + S3;
  const uint16_t* fw3T = wsb + EDGE_FRAGS + S3 + S4;

  hipMemsetAsync(agg, 0, 9600 * 192 * sizeof(float), stream);
  prep_kernel<<<(PREP_TOTAL + 255) / 256, 256, 0, stream>>>(
      few1, feb1, few2, few3, fnw1, fnw2, fnw3, wsb);
  edge_kernel<<<EDGE_BLOCKS, 1024, 0, stream>>>(x, feb2, feb3, wfe, agg);
  node_kernel<<<150, 512, 0, stream>>>(x, agg, fnb1, fnb2, fnb3, fw1T, fw2T, fw3T, out);
}